// Round 5
// baseline (1468.677 us; speedup 1.0000x reference)
//
#include <hip/hip_runtime.h>

#define NN 100000     // nodes
#define NE 1600000    // edges
#define NG 512        // graphs
#define C_H1 64
#define C_H2 128
#define C_OUT 2

#define SCAN_CHUNK 512
#define SCAN_B ((NN + SCAN_CHUNK - 1) / SCAN_CHUNK)   // 196

// ---------------- degree histogram (at dst) ----------------
__global__ void k_deg(const int* __restrict__ ei, int* __restrict__ deg) {
    int e = blockIdx.x * blockDim.x + threadIdx.x;
    if (e < NE) atomicAdd(&deg[ei[NE + e]], 1);
}

__global__ void k_dinv(const int* __restrict__ deg, float* __restrict__ dinv) {
    int i = blockIdx.x * blockDim.x + threadIdx.x;
    if (i < NN) dinv[i] = rsqrtf((float)deg[i] + 1.0f);
}

// ---------------- hierarchical scan phase 1: per-block sums ----------------
__global__ void k_bsum(const int* __restrict__ deg, int* __restrict__ bsum) {
    __shared__ int sh[256];
    int tid = threadIdx.x;
    int base = blockIdx.x * SCAN_CHUNK + tid * 2;
    int s = 0;
    if (base < NN)     s += deg[base];
    if (base + 1 < NN) s += deg[base + 1];
    sh[tid] = s;
    __syncthreads();
    for (int off = 128; off > 0; off >>= 1) {
        if (tid < off) sh[tid] += sh[tid + off];
        __syncthreads();
    }
    if (tid == 0) bsum[blockIdx.x] = sh[0];
}

// ---------------- phase 2: single small block scans the 196 block sums -----------
__global__ void k_bscan(const int* __restrict__ bsum, int* __restrict__ boff,
                        int* __restrict__ row_ptr) {
    __shared__ int sh[256];
    int tid = threadIdx.x;
    sh[tid] = (tid < SCAN_B) ? bsum[tid] : 0;
    __syncthreads();
    for (int off = 1; off < 256; off <<= 1) {
        int v = (tid >= off) ? sh[tid - off] : 0;
        __syncthreads();
        sh[tid] += v;
        __syncthreads();
    }
    if (tid < SCAN_B) boff[tid] = (tid == 0) ? 0 : sh[tid - 1];
    if (tid == 255) row_ptr[NN] = sh[SCAN_B - 1];   // total == NE
}

// ---------------- phase 3: in-block exclusive scan + write row_ptr/cursor --------
__global__ void k_bwrite(const int* __restrict__ deg, const int* __restrict__ boff,
                         int* __restrict__ row_ptr, int* __restrict__ cursor) {
    __shared__ int sh[256];
    int tid = threadIdx.x;
    int base = blockIdx.x * SCAN_CHUNK + tid * 2;
    int d0 = (base < NN)     ? deg[base]     : 0;
    int d1 = (base + 1 < NN) ? deg[base + 1] : 0;
    sh[tid] = d0 + d1;
    __syncthreads();
    for (int off = 1; off < 256; off <<= 1) {
        int v = (tid >= off) ? sh[tid - off] : 0;
        __syncthreads();
        sh[tid] += v;
        __syncthreads();
    }
    int excl = boff[blockIdx.x] + ((tid == 0) ? 0 : sh[tid - 1]);
    if (base < NN)     { row_ptr[base]     = excl;      cursor[base]     = excl; }
    if (base + 1 < NN) { row_ptr[base + 1] = excl + d0; cursor[base + 1] = excl + d0; }
}

// ---------------- scatter edges into dst-CSR: packed (src, norm) ----------------
__global__ void k_scatter(const int* __restrict__ ei, const float* __restrict__ dinv,
                          int* __restrict__ cursor, int2* __restrict__ ed) {
    int e = blockIdx.x * blockDim.x + threadIdx.x;
    if (e >= NE) return;
    int s = ei[e], d = ei[NE + e];
    int pos = atomicAdd(&cursor[d], 1);
    int2 v; v.x = s; v.y = __float_as_int(dinv[s] * dinv[d]);
    ed[pos] = v;
}

// ---------------- layer 1 aggregate FIRST (3 channels, x is L2-resident) ----------
__global__ void k_aggx(const int* __restrict__ row_ptr, const int2* __restrict__ ed,
                       const float* __restrict__ dinv, const float* __restrict__ x,
                       float* __restrict__ aggx) {
    int n = blockIdx.x * blockDim.x + threadIdx.x;
    if (n >= NN) return;
    float di = dinv[n];
    float s2 = di * di;
    float a0 = s2 * x[n * 3], a1 = s2 * x[n * 3 + 1], a2 = s2 * x[n * 3 + 2];
    int beg = row_ptr[n], end = row_ptr[n + 1];
    for (int j = beg; j < end; ++j) {
        int2 v = ed[j];
        float w = __int_as_float(v.y);
        const float* xs = x + v.x * 3;
        a0 = fmaf(w, xs[0], a0);
        a1 = fmaf(w, xs[1], a1);
        a2 = fmaf(w, xs[2], a2);
    }
    aggx[n * 3]     = a0;
    aggx[n * 3 + 1] = a1;
    aggx[n * 3 + 2] = a2;
}

// ---------------- h1 = relu(aggx @ W1 + b1) ----------------
__global__ void k_h1(const float* __restrict__ aggx, const float* __restrict__ W1,
                     const float* __restrict__ b1, float* __restrict__ h1) {
    int t = blockIdx.x * blockDim.x + threadIdx.x;
    if (t >= NN * C_H1) return;
    int n = t >> 6, c = t & 63;
    float v = aggx[n * 3] * W1[c] + aggx[n * 3 + 1] * W1[64 + c]
            + aggx[n * 3 + 2] * W1[128 + c] + b1[c];
    h1[t] = fmaxf(v, 0.f);
}

// ---------------- layer 2 aggregate (64 channels): agg1 = Ahat @ h1 --------------
__global__ void k_gather2(const int* __restrict__ row_ptr, const int2* __restrict__ ed,
                          const float* __restrict__ dinv, const float* __restrict__ h1,
                          float* __restrict__ agg1) {
    int t = blockIdx.x * blockDim.x + threadIdx.x;   // wave = one node (64 ch)
    if (t >= NN * C_H1) return;
    int n = t >> 6, c = t & 63;
    float di = dinv[n];
    float acc = di * di * h1[t];                     // self-loop
    int beg = row_ptr[n], end = row_ptr[n + 1];
    int j = beg;
    // unroll x8: more outstanding loads in this latency-bound gather
    for (; j + 7 < end; j += 8) {
        int2 v0 = ed[j],     v1 = ed[j + 1], v2 = ed[j + 2], v3 = ed[j + 3];
        int2 v4 = ed[j + 4], v5 = ed[j + 5], v6 = ed[j + 6], v7 = ed[j + 7];
        float f0 = h1[(v0.x << 6) + c];
        float f1 = h1[(v1.x << 6) + c];
        float f2 = h1[(v2.x << 6) + c];
        float f3 = h1[(v3.x << 6) + c];
        float f4 = h1[(v4.x << 6) + c];
        float f5 = h1[(v5.x << 6) + c];
        float f6 = h1[(v6.x << 6) + c];
        float f7 = h1[(v7.x << 6) + c];
        acc = fmaf(__int_as_float(v0.y), f0, acc);
        acc = fmaf(__int_as_float(v1.y), f1, acc);
        acc = fmaf(__int_as_float(v2.y), f2, acc);
        acc = fmaf(__int_as_float(v3.y), f3, acc);
        acc = fmaf(__int_as_float(v4.y), f4, acc);
        acc = fmaf(__int_as_float(v5.y), f5, acc);
        acc = fmaf(__int_as_float(v6.y), f6, acc);
        acc = fmaf(__int_as_float(v7.y), f7, acc);
    }
    for (; j < end; ++j) {
        int2 v = ed[j];
        acc = fmaf(__int_as_float(v.y), h1[(v.x << 6) + c], acc);
    }
    agg1[t] = acc;   // NO bias/relu here: h2 = relu(agg1 @ W2 + b2)
}

// ---------------- fused: h2 = relu(agg1 @ W2 + b2), pooled += h2 -----------------
// Register-blocked: 256 threads = 2 slots x 128 ch; each thread does 8 nodes.
// W2 value from LDS reused across 8 nodes; agg1 rows via wave-uniform float4.
__global__ void k_mm2pool(const float* __restrict__ agg1, const float* __restrict__ W2,
                          const float* __restrict__ b2, const int* __restrict__ batch,
                          float* __restrict__ pooled) {
    __shared__ float w[C_H1 * C_H2];                 // 32 KiB
    int tid = threadIdx.x;
    for (int i = tid; i < C_H1 * C_H2; i += 256) w[i] = W2[i];
    __syncthreads();
    int c = tid & 127, slot = tid >> 7;
    int base = blockIdx.x * 16 + slot * 8;           // 8 consecutive nodes
    const float4* a4 = (const float4*)(agg1 + ((size_t)base << 6));  // 8 rows, 16 float4 each
    float acc[8] = {0.f, 0.f, 0.f, 0.f, 0.f, 0.f, 0.f, 0.f};
    for (int kk = 0; kk < 16; ++kk) {                // k = 4*kk .. 4*kk+3
        float4 av[8];
#pragma unroll
        for (int n = 0; n < 8; ++n) av[n] = a4[n * 16 + kk];
        float w0 = w[(kk * 4 + 0) * C_H2 + c];
        float w1 = w[(kk * 4 + 1) * C_H2 + c];
        float w2 = w[(kk * 4 + 2) * C_H2 + c];
        float w3 = w[(kk * 4 + 3) * C_H2 + c];
#pragma unroll
        for (int n = 0; n < 8; ++n) {
            acc[n] = fmaf(av[n].x, w0, acc[n]);
            acc[n] = fmaf(av[n].y, w1, acc[n]);
            acc[n] = fmaf(av[n].z, w2, acc[n]);
            acc[n] = fmaf(av[n].w, w3, acc[n]);
        }
    }
    float bias = b2[c];
    int run_g = -1;
    float run_sum = 0.f;
#pragma unroll
    for (int n = 0; n < 8; ++n) {
        float h2 = fmaxf(acc[n] + bias, 0.f);
        int g = batch[base + n];
        if (g != run_g) {
            if (run_g >= 0) atomicAdd(&pooled[(run_g << 7) + c], run_sum);
            run_g = g; run_sum = h2;
        } else {
            run_sum += h2;
        }
    }
    if (run_g >= 0) atomicAdd(&pooled[(run_g << 7) + c], run_sum);
}

// ---------------- FC: out = (pooled/cnt) @ Wfc + bfc ----------------
__device__ __forceinline__ int lower_bound(const int* __restrict__ a, int n, int key) {
    int lo = 0, hi = n;
    while (lo < hi) { int mid = (lo + hi) >> 1; if (a[mid] < key) lo = mid + 1; else hi = mid; }
    return lo;
}

__global__ void k_fc(const float* __restrict__ pooled, const int* __restrict__ batch,
                     const float* __restrict__ Wfc, const float* __restrict__ bfc,
                     float* __restrict__ out) {
    int t = blockIdx.x * blockDim.x + threadIdx.x;
    if (t >= NG * C_OUT) return;
    int g = t >> 1, o = t & 1;
    int start = lower_bound(batch, NN, g);
    int end   = lower_bound(batch, NN, g + 1);
    float inv = 1.f / fmaxf((float)(end - start), 1.f);
    float s = bfc[o];
    for (int cc = 0; cc < C_H2; ++cc)
        s = fmaf(pooled[(g << 7) + cc] * inv, Wfc[cc * C_OUT + o], s);
    out[t] = s;
}

extern "C" void kernel_launch(void* const* d_in, const int* in_sizes, int n_in,
                              void* d_out, int out_size, void* d_ws, size_t ws_size,
                              hipStream_t stream) {
    const float* x     = (const float*)d_in[0];
    const int*   ei    = (const int*)d_in[1];   // [2, E]: row0 = src, row1 = dst
    const int*   batch = (const int*)d_in[2];
    const float* W1    = (const float*)d_in[3];
    const float* b1    = (const float*)d_in[4];
    const float* W2    = (const float*)d_in[5];
    const float* b2    = (const float*)d_in[6];
    const float* Wfc   = (const float*)d_in[7];
    const float* bfc   = (const float*)d_in[8];
    float* out = (float*)d_out;

    // workspace carve-out (~66 MB)
    char* p = (char*)d_ws;
    auto alloc = [&](size_t bytes) { char* r = p; p += (bytes + 255) & ~size_t(255); return r; };
    int*   deg     = (int*)  alloc((size_t)NN * 4);
    float* dinv    = (float*)alloc((size_t)NN * 4);
    int*   row_ptr = (int*)  alloc((size_t)(NN + 1) * 4);
    int*   cursor  = (int*)  alloc((size_t)NN * 4);
    int*   bsum    = (int*)  alloc((size_t)SCAN_B * 4);
    int*   boff    = (int*)  alloc((size_t)SCAN_B * 4);
    int2*  ed      = (int2*) alloc((size_t)NE * 8);
    float* aggx    = (float*)alloc((size_t)NN * 3 * 4);
    float* h1      = (float*)alloc((size_t)NN * C_H1 * 4);
    float* agg1    = (float*)alloc((size_t)NN * C_H1 * 4);
    float* pooled  = (float*)alloc((size_t)NG * C_H2 * 4);

    hipMemsetAsync(deg, 0, (size_t)NN * 4, stream);
    hipMemsetAsync(pooled, 0, (size_t)NG * C_H2 * 4, stream);
    k_deg    <<<NE / 256, 256, 0, stream>>>(ei, deg);
    k_dinv   <<<(NN + 255) / 256, 256, 0, stream>>>(deg, dinv);
    k_bsum   <<<SCAN_B, 256, 0, stream>>>(deg, bsum);
    k_bscan  <<<1, 256, 0, stream>>>(bsum, boff, row_ptr);
    k_bwrite <<<SCAN_B, 256, 0, stream>>>(deg, boff, row_ptr, cursor);
    k_scatter<<<NE / 256, 256, 0, stream>>>(ei, dinv, cursor, ed);
    k_aggx   <<<(NN + 255) / 256, 256, 0, stream>>>(row_ptr, ed, dinv, x, aggx);
    k_h1     <<<(NN * C_H1) / 256, 256, 0, stream>>>(aggx, W1, b1, h1);
    k_gather2<<<(NN * C_H1) / 256, 256, 0, stream>>>(row_ptr, ed, dinv, h1, agg1);
    k_mm2pool<<<NN / 16, 256, 0, stream>>>(agg1, W2, b2, batch, pooled);
    k_fc     <<<(NG * C_OUT + 255) / 256, 256, 0, stream>>>(pooled, batch, Wfc, bfc, out);
}

// Round 6
// 401.879 us; speedup vs baseline: 3.6545x; 3.6545x over previous
//
#include <hip/hip_runtime.h>

#define NN 100000     // nodes
#define NE 1600000    // edges
#define NG 512        // graphs
#define C_H1 64
#define C_H2 128
#define C_OUT 2

#define SCAN_CHUNK 512
#define SCAN_B ((NN + SCAN_CHUNK - 1) / SCAN_CHUNK)   // 196
#define MM2_BLOCKS ((NN + 63) / 64)                   // 1563

// ---------------- degree histogram (at dst) ----------------
__global__ void k_deg(const int* __restrict__ ei, int* __restrict__ deg) {
    int e = blockIdx.x * blockDim.x + threadIdx.x;
    if (e < NE) atomicAdd(&deg[ei[NE + e]], 1);
}

__global__ void k_dinv(const int* __restrict__ deg, float* __restrict__ dinv) {
    int i = blockIdx.x * blockDim.x + threadIdx.x;
    if (i < NN) dinv[i] = rsqrtf((float)deg[i] + 1.0f);
}

// ---------------- hierarchical scan phase 1: per-block sums ----------------
__global__ void k_bsum(const int* __restrict__ deg, int* __restrict__ bsum) {
    __shared__ int sh[256];
    int tid = threadIdx.x;
    int base = blockIdx.x * SCAN_CHUNK + tid * 2;
    int s = 0;
    if (base < NN)     s += deg[base];
    if (base + 1 < NN) s += deg[base + 1];
    sh[tid] = s;
    __syncthreads();
    for (int off = 128; off > 0; off >>= 1) {
        if (tid < off) sh[tid] += sh[tid + off];
        __syncthreads();
    }
    if (tid == 0) bsum[blockIdx.x] = sh[0];
}

// ---------------- phase 2: single small block scans the 196 block sums -----------
__global__ void k_bscan(const int* __restrict__ bsum, int* __restrict__ boff,
                        int* __restrict__ row_ptr) {
    __shared__ int sh[256];
    int tid = threadIdx.x;
    sh[tid] = (tid < SCAN_B) ? bsum[tid] : 0;
    __syncthreads();
    for (int off = 1; off < 256; off <<= 1) {
        int v = (tid >= off) ? sh[tid - off] : 0;
        __syncthreads();
        sh[tid] += v;
        __syncthreads();
    }
    if (tid < SCAN_B) boff[tid] = (tid == 0) ? 0 : sh[tid - 1];
    if (tid == 255) row_ptr[NN] = sh[SCAN_B - 1];   // total == NE
}

// ---------------- phase 3: in-block exclusive scan + write row_ptr/cursor --------
__global__ void k_bwrite(const int* __restrict__ deg, const int* __restrict__ boff,
                         int* __restrict__ row_ptr, int* __restrict__ cursor) {
    __shared__ int sh[256];
    int tid = threadIdx.x;
    int base = blockIdx.x * SCAN_CHUNK + tid * 2;
    int d0 = (base < NN)     ? deg[base]     : 0;
    int d1 = (base + 1 < NN) ? deg[base + 1] : 0;
    sh[tid] = d0 + d1;
    __syncthreads();
    for (int off = 1; off < 256; off <<= 1) {
        int v = (tid >= off) ? sh[tid - off] : 0;
        __syncthreads();
        sh[tid] += v;
        __syncthreads();
    }
    int excl = boff[blockIdx.x] + ((tid == 0) ? 0 : sh[tid - 1]);
    if (base < NN)     { row_ptr[base]     = excl;      cursor[base]     = excl; }
    if (base + 1 < NN) { row_ptr[base + 1] = excl + d0; cursor[base + 1] = excl + d0; }
}

// ---------------- scatter edges into dst-CSR: packed (src, norm) ----------------
__global__ void k_scatter(const int* __restrict__ ei, const float* __restrict__ dinv,
                          int* __restrict__ cursor, int2* __restrict__ ed) {
    int e = blockIdx.x * blockDim.x + threadIdx.x;
    if (e >= NE) return;
    int s = ei[e], d = ei[NE + e];
    int pos = atomicAdd(&cursor[d], 1);
    int2 v; v.x = s; v.y = __float_as_int(dinv[s] * dinv[d]);
    ed[pos] = v;
}

// ---------------- layer 1 aggregate FIRST (3 channels, x is L2-resident) ----------
__global__ void k_aggx(const int* __restrict__ row_ptr, const int2* __restrict__ ed,
                       const float* __restrict__ dinv, const float* __restrict__ x,
                       float* __restrict__ aggx) {
    int n = blockIdx.x * blockDim.x + threadIdx.x;
    if (n >= NN) return;
    float di = dinv[n];
    float s2 = di * di;
    float a0 = s2 * x[n * 3], a1 = s2 * x[n * 3 + 1], a2 = s2 * x[n * 3 + 2];
    int beg = row_ptr[n], end = row_ptr[n + 1];
    for (int j = beg; j < end; ++j) {
        int2 v = ed[j];
        float w = __int_as_float(v.y);
        const float* xs = x + v.x * 3;
        a0 = fmaf(w, xs[0], a0);
        a1 = fmaf(w, xs[1], a1);
        a2 = fmaf(w, xs[2], a2);
    }
    aggx[n * 3]     = a0;
    aggx[n * 3 + 1] = a1;
    aggx[n * 3 + 2] = a2;
}

// ---------------- h1 = relu(aggx @ W1 + b1) ----------------
__global__ void k_h1(const float* __restrict__ aggx, const float* __restrict__ W1,
                     const float* __restrict__ b1, float* __restrict__ h1) {
    int t = blockIdx.x * blockDim.x + threadIdx.x;
    if (t >= NN * C_H1) return;
    int n = t >> 6, c = t & 63;
    float v = aggx[n * 3] * W1[c] + aggx[n * 3 + 1] * W1[64 + c]
            + aggx[n * 3 + 2] * W1[128 + c] + b1[c];
    h1[t] = fmaxf(v, 0.f);
}

// ---------------- layer 2 aggregate (64 channels): agg1 = Ahat @ h1 --------------
// (round-4 version: x4 unroll, per-lane coalesced h1 reads)
__global__ void k_gather2(const int* __restrict__ row_ptr, const int2* __restrict__ ed,
                          const float* __restrict__ dinv, const float* __restrict__ h1,
                          float* __restrict__ agg1) {
    int t = blockIdx.x * blockDim.x + threadIdx.x;   // wave = one node (64 ch)
    if (t >= NN * C_H1) return;
    int n = t >> 6, c = t & 63;
    float di = dinv[n];
    float acc = di * di * h1[t];                     // self-loop
    int beg = row_ptr[n], end = row_ptr[n + 1];
    int j = beg;
    for (; j + 3 < end; j += 4) {
        int2 v0 = ed[j], v1 = ed[j + 1], v2 = ed[j + 2], v3 = ed[j + 3];
        float f0 = h1[(v0.x << 6) + c];
        float f1 = h1[(v1.x << 6) + c];
        float f2 = h1[(v2.x << 6) + c];
        float f3 = h1[(v3.x << 6) + c];
        acc = fmaf(__int_as_float(v0.y), f0, acc);
        acc = fmaf(__int_as_float(v1.y), f1, acc);
        acc = fmaf(__int_as_float(v2.y), f2, acc);
        acc = fmaf(__int_as_float(v3.y), f3, acc);
    }
    for (; j < end; ++j) {
        int2 v = ed[j];
        acc = fmaf(__int_as_float(v.y), h1[(v.x << 6) + c], acc);
    }
    agg1[t] = acc;   // NO bias/relu here: h2 = relu(agg1 @ W2 + b2)
}

// ---------------- fused register-tiled GEMM + pool --------------------------------
// Block = 64 nodes x 128 ch, 256 threads, 8x4 micro-tile per thread.
// A-tile (16 KB) + W2 (32 KB) staged in LDS via coalesced float4.
__global__ void k_mm2pool(const float* __restrict__ agg1, const float* __restrict__ W2,
                          const float* __restrict__ b2, const int* __restrict__ batch,
                          float* __restrict__ pooled) {
    __shared__ float wt[C_H1 * C_H2];   // 32 KiB
    __shared__ float at[64 * C_H1];     // 16 KiB
    int tid = threadIdx.x;
    {
        const float4* w4 = (const float4*)W2;
        float4* wl = (float4*)wt;
        for (int i = tid; i < (C_H1 * C_H2) / 4; i += 256) wl[i] = w4[i];
        const float4* a4 = (const float4*)(agg1 + (size_t)blockIdx.x * 64 * C_H1);
        float4* al = (float4*)at;
        for (int i = tid; i < (64 * C_H1) / 4; i += 256) al[i] = a4[i];
    }
    __syncthreads();

    int tx = tid & 31;           // channel group: c0..c0+3
    int my = tid >> 5;           // row group: m0..m0+7
    int c0 = tx * 4;
    int m0 = my * 8;

    float acc[8][4];
#pragma unroll
    for (int i = 0; i < 8; ++i)
#pragma unroll
        for (int j = 0; j < 4; ++j) acc[i][j] = 0.f;

    for (int k0 = 0; k0 < C_H1; k0 += 4) {
        float4 wf[4];
#pragma unroll
        for (int kk = 0; kk < 4; ++kk)
            wf[kk] = *(const float4*)&wt[(k0 + kk) * C_H2 + c0];
#pragma unroll
        for (int i = 0; i < 8; ++i) {
            float4 af = *(const float4*)&at[(m0 + i) * C_H1 + k0];
            acc[i][0] = fmaf(af.x, wf[0].x, acc[i][0]);
            acc[i][1] = fmaf(af.x, wf[0].y, acc[i][1]);
            acc[i][2] = fmaf(af.x, wf[0].z, acc[i][2]);
            acc[i][3] = fmaf(af.x, wf[0].w, acc[i][3]);
            acc[i][0] = fmaf(af.y, wf[1].x, acc[i][0]);
            acc[i][1] = fmaf(af.y, wf[1].y, acc[i][1]);
            acc[i][2] = fmaf(af.y, wf[1].z, acc[i][2]);
            acc[i][3] = fmaf(af.y, wf[1].w, acc[i][3]);
            acc[i][0] = fmaf(af.z, wf[2].x, acc[i][0]);
            acc[i][1] = fmaf(af.z, wf[2].y, acc[i][1]);
            acc[i][2] = fmaf(af.z, wf[2].z, acc[i][2]);
            acc[i][3] = fmaf(af.z, wf[2].w, acc[i][3]);
            acc[i][0] = fmaf(af.w, wf[3].x, acc[i][0]);
            acc[i][1] = fmaf(af.w, wf[3].y, acc[i][1]);
            acc[i][2] = fmaf(af.w, wf[3].z, acc[i][2]);
            acc[i][3] = fmaf(af.w, wf[3].w, acc[i][3]);
        }
    }

    // epilogue: bias + relu + run-length pooled atomics
    int nbase = blockIdx.x * 64 + m0;
    int gidx[8];
#pragma unroll
    for (int i = 0; i < 8; ++i)
        gidx[i] = (nbase + i < NN) ? batch[nbase + i] : -1;
    float bias[4];
#pragma unroll
    for (int j = 0; j < 4; ++j) bias[j] = b2[c0 + j];

#pragma unroll
    for (int j = 0; j < 4; ++j) {
        int run_g = -1;
        float rs = 0.f;
#pragma unroll
        for (int i = 0; i < 8; ++i) {
            if (gidx[i] < 0) break;
            float h = fmaxf(acc[i][j] + bias[j], 0.f);
            if (gidx[i] != run_g) {
                if (run_g >= 0) atomicAdd(&pooled[(run_g << 7) + c0 + j], rs);
                run_g = gidx[i]; rs = h;
            } else {
                rs += h;
            }
        }
        if (run_g >= 0) atomicAdd(&pooled[(run_g << 7) + c0 + j], rs);
    }
}

// ---------------- FC: out = (pooled/cnt) @ Wfc + bfc ----------------
__device__ __forceinline__ int lower_bound(const int* __restrict__ a, int n, int key) {
    int lo = 0, hi = n;
    while (lo < hi) { int mid = (lo + hi) >> 1; if (a[mid] < key) lo = mid + 1; else hi = mid; }
    return lo;
}

__global__ void k_fc(const float* __restrict__ pooled, const int* __restrict__ batch,
                     const float* __restrict__ Wfc, const float* __restrict__ bfc,
                     float* __restrict__ out) {
    int t = blockIdx.x * blockDim.x + threadIdx.x;
    if (t >= NG * C_OUT) return;
    int g = t >> 1, o = t & 1;
    int start = lower_bound(batch, NN, g);
    int end   = lower_bound(batch, NN, g + 1);
    float inv = 1.f / fmaxf((float)(end - start), 1.f);
    float s = bfc[o];
    for (int cc = 0; cc < C_H2; ++cc)
        s = fmaf(pooled[(g << 7) + cc] * inv, Wfc[cc * C_OUT + o], s);
    out[t] = s;
}

extern "C" void kernel_launch(void* const* d_in, const int* in_sizes, int n_in,
                              void* d_out, int out_size, void* d_ws, size_t ws_size,
                              hipStream_t stream) {
    const float* x     = (const float*)d_in[0];
    const int*   ei    = (const int*)d_in[1];   // [2, E]: row0 = src, row1 = dst
    const int*   batch = (const int*)d_in[2];
    const float* W1    = (const float*)d_in[3];
    const float* b1    = (const float*)d_in[4];
    const float* W2    = (const float*)d_in[5];
    const float* b2    = (const float*)d_in[6];
    const float* Wfc   = (const float*)d_in[7];
    const float* bfc   = (const float*)d_in[8];
    float* out = (float*)d_out;

    // workspace carve-out (~66 MB); agg1 padded to a 64-row multiple for k_mm2pool
    char* p = (char*)d_ws;
    auto alloc = [&](size_t bytes) { char* r = p; p += (bytes + 255) & ~size_t(255); return r; };
    int*   deg     = (int*)  alloc((size_t)NN * 4);
    float* dinv    = (float*)alloc((size_t)NN * 4);
    int*   row_ptr = (int*)  alloc((size_t)(NN + 1) * 4);
    int*   cursor  = (int*)  alloc((size_t)NN * 4);
    int*   bsum    = (int*)  alloc((size_t)SCAN_B * 4);
    int*   boff    = (int*)  alloc((size_t)SCAN_B * 4);
    int2*  ed      = (int2*) alloc((size_t)NE * 8);
    float* aggx    = (float*)alloc((size_t)NN * 3 * 4);
    float* h1      = (float*)alloc((size_t)NN * C_H1 * 4);
    float* agg1    = (float*)alloc((size_t)(NN + 64) * C_H1 * 4);  // padded
    float* pooled  = (float*)alloc((size_t)NG * C_H2 * 4);

    hipMemsetAsync(deg, 0, (size_t)NN * 4, stream);
    hipMemsetAsync(pooled, 0, (size_t)NG * C_H2 * 4, stream);
    k_deg    <<<NE / 256, 256, 0, stream>>>(ei, deg);
    k_dinv   <<<(NN + 255) / 256, 256, 0, stream>>>(deg, dinv);
    k_bsum   <<<SCAN_B, 256, 0, stream>>>(deg, bsum);
    k_bscan  <<<1, 256, 0, stream>>>(bsum, boff, row_ptr);
    k_bwrite <<<SCAN_B, 256, 0, stream>>>(deg, boff, row_ptr, cursor);
    k_scatter<<<NE / 256, 256, 0, stream>>>(ei, dinv, cursor, ed);
    k_aggx   <<<(NN + 255) / 256, 256, 0, stream>>>(row_ptr, ed, dinv, x, aggx);
    k_h1     <<<(NN * C_H1) / 256, 256, 0, stream>>>(aggx, W1, b1, h1);
    k_gather2<<<(NN * C_H1) / 256, 256, 0, stream>>>(row_ptr, ed, dinv, h1, agg1);
    k_mm2pool<<<MM2_BLOCKS, 256, 0, stream>>>(agg1, W2, b2, batch, pooled);
    k_fc     <<<(NG * C_OUT + 255) / 256, 256, 0, stream>>>(pooled, batch, Wfc, bfc, out);
}